// Round 4
// baseline (736.748 us; speedup 1.0000x reference)
//
#include <hip/hip_runtime.h>
#include <math.h>

// Problem constants (from reference)
constexpr int BS = 16384;
constexpr int NC = 8192;
constexpr int THREADS = 256;

constexpr int CHUNK_F4 = 8;                          // float4 per lane per chunk

using f4 = __attribute__((ext_vector_type(4))) float;

__device__ __forceinline__ float ex2(float a) { return __builtin_amdgcn_exp2f(a); }

// ---------------------------------------------------------------------------
// Pass 1: one WAVE per row (4 rows per 256-thread block). Identical math to
// R3 (verified, absmax 0). `reps` added for the R4 measurement probe: the
// whole row stream + reduction + write repeats `reps` times (x is re-fetched
// from HBM each rep since 512 MiB > 256 MiB L3). reps=1 is the real pass.
// ---------------------------------------------------------------------------
__launch_bounds__(THREADS, 4)
__global__ void self_filter_row_kernel(const float* __restrict__ x,
                                       const int* __restrict__ tgt,
                                       float* __restrict__ partial,
                                       int reps) {
    const int t    = threadIdx.x;
    const int wave = t >> 6;
    const int lane = t & 63;
    const int row  = (blockIdx.x << 2) | wave;       // grid = BS/4 blocks

    const f4* rowp = reinterpret_cast<const f4*>(x + (size_t)row * NC);
    const int   tr = tgt[row];                       // wave-uniform
    const float xt = x[(size_t)row * NC + tr];       // wave-uniform scalar

    const float L  = 1.4426950408889634f;            // log2(e)
    const float yt = xt * L;

    f4 A[CHUNK_F4], B[CHUNK_F4];

#define LOADC(buf, c)                                                       \
    _Pragma("unroll")                                                       \
    for (int i = 0; i < CHUNK_F4; ++i)                                      \
        buf[i] = __builtin_nontemporal_load(                                \
            &rowp[(c) * (64 * CHUNK_F4) + i * 64 + lane]);

#define PROCC(buf)                                                          \
    {                                                                       \
        float cm = -INFINITY;                                               \
        _Pragma("unroll")                                                   \
        for (int i = 0; i < CHUNK_F4; ++i)                                  \
            cm = fmaxf(cm, fmaxf(fmaxf(buf[i][0], buf[i][1]),               \
                                 fmaxf(buf[i][2], buf[i][3])));             \
        const float mn = fmaxf(my, cm * L);                                 \
        se *= ex2(my - mn);           /* rescale old sum; first chunk: 0 */ \
        my = mn;                                                            \
        const float Kc = ex2(my - yt);                                      \
        _Pragma("unroll")                                                   \
        for (int i = 0; i < CHUNK_F4; ++i) {                                \
            _Pragma("unroll")                                               \
            for (int k = 0; k < 4; ++k) {                                   \
                const float xv = buf[i][k];                                 \
                const float e  = ex2(fmaf(xv, L, -my)); /* exp(xv-mx) */    \
                se += e;                                                    \
                const float conf = fmaf(e, -Kc, 0.2f);  /* 0.2 - p/pt */    \
                const float lat  = fmaxf(conf, 0.0f);                       \
                sxl = fmaf(xv, lat, sxl);                                   \
                sl += lat;                                                  \
            }                                                               \
        }                                                                   \
    }

    for (int r = 0; r < reps; ++r) {
        float my = -INFINITY;                        // running max (exp2 domain)
        float se = 0.0f, sxl = 0.0f, sl = 0.0f;

        // ---- 1-deep software-pipelined chunk stream (4 chunks, ping-pong)
        LOADC(A, 0);
        LOADC(B, 1);
        PROCC(A);          // B's loads in flight under A's compute
        LOADC(A, 2);
        PROCC(B);          // A(c2) in flight
        LOADC(B, 3);
        PROCC(A);          // B(c3) in flight
        PROCC(B);

        // ---- Cross-lane butterfly: online-softmax merge (my,se); plain sums
#pragma unroll
        for (int off = 32; off > 0; off >>= 1) {
            const float my2 = __shfl_xor(my, off, 64);
            const float se2 = __shfl_xor(se, off, 64);
            const float mn  = fmaxf(my, my2);
            se = se * ex2(my - mn) + se2 * ex2(my2 - mn);
            my = mn;
            sxl += __shfl_xor(sxl, off, 64);
            sl  += __shfl_xor(sl,  off, 64);
        }

        if (lane == 0) {
            const float LN2  = 0.69314718055994531f;
            const float off_ = LN2 * (my + __builtin_amdgcn_logf(se));
            const float total = sxl - off_ * sl;   // sum_j log_prob_j * latent_j
            const float lp_t  = xt - off_;
            partial[row] = -lp_t - (0.1f / (float)(NC - 1)) * total;
        }
    }

#undef LOADC
#undef PROCC
}

// ---------------------------------------------------------------------------
// Pass 2: one block sums the 16384 per-row partials and writes the scalar.
// (d_out is poisoned by the harness — we fully overwrite it.)
// ---------------------------------------------------------------------------
__launch_bounds__(THREADS)
__global__ void self_filter_reduce_kernel(const float* __restrict__ partial,
                                          float* __restrict__ out) {
    const int t    = threadIdx.x;
    const int wave = t >> 6;
    const int lane = t & 63;
    __shared__ float s_s[4];

    const f4* p4 = reinterpret_cast<const f4*>(partial);
    float s = 0.0f;
#pragma unroll
    for (int i = 0; i < BS / (THREADS * 4); ++i) {   // 16 float4 per thread
        const f4 v = p4[i * THREADS + t];
        s += (v[0] + v[1]) + (v[2] + v[3]);
    }
#pragma unroll
    for (int off = 32; off > 0; off >>= 1)
        s += __shfl_xor(s, off, 64);
    if (lane == 0) s_s[wave] = s;
    __syncthreads();
    if (t == 0)
        out[0] = (s_s[0] + s_s[1] + s_s[2] + s_s[3]) * (1.0f / (float)BS);
}

extern "C" void kernel_launch(void* const* d_in, const int* in_sizes, int n_in,
                              void* d_out, int out_size, void* d_ws, size_t ws_size,
                              hipStream_t stream) {
    const float* x   = (const float*)d_in[0];
    const int*   tgt = (const int*)d_in[1];
    float*       out = (float*)d_out;
    float*       partial  = (float*)d_ws;            // 64 KiB scratch (verified path)
    float*       partial2 = (float*)d_ws + BS;       // disjoint 64 KiB (probe only)

    // Real computation (unchanged from R3):
    self_filter_row_kernel<<<BS / 4, THREADS, 0, stream>>>(x, tgt, partial, 1);
    self_filter_reduce_kernel<<<1, THREADS, 0, stream>>>(partial, out);

    // MEASUREMENT PROBE (R4): same kernel, 3 full HBM passes, writes scratch.
    // Runs >400 us as one dispatch -> guaranteed to surface in rocprof top-5
    // with its own dur/hbm_gbps/FETCH_SIZE/VALUBusy/Occupancy. Remove in R5.
    self_filter_row_kernel<<<BS / 4, THREADS, 0, stream>>>(x, tgt, partial2, 3);
}